// Round 1
// baseline (614.988 us; speedup 1.0000x reference)
//
#include <hip/hip_runtime.h>
#include <hip/hip_bf16.h>

// Basic_Transformer on MI355X (gfx950): bf16 MFMA pipeline.
// B=2 S=2048 C=512 L=4 H=8 CH=64 OD=256; rows M = B*S = 4096.

typedef __bf16 bf16_t;
typedef __attribute__((ext_vector_type(8))) __bf16 bf16x8;
typedef __attribute__((ext_vector_type(4))) __bf16 bf16x4;
typedef __attribute__((ext_vector_type(4))) float f32x4;

#define MROWS 4096

static __device__ __forceinline__ void gload_lds16(const void* g, void* l) {
  __builtin_amdgcn_global_load_lds((const __attribute__((address_space(1))) void*)g,
                                   (__attribute__((address_space(3))) void*)l, 16, 0, 0);
}

// ---------------- layernorm: one wave per row (64 lanes x 8 f32) ----------------
__global__ __launch_bounds__(256) void ln_kernel(const float* __restrict__ xin,
    const float* __restrict__ gamma, const float* __restrict__ beta,
    bf16_t* __restrict__ hout)
{
  int w = threadIdx.x >> 6, l = threadIdx.x & 63;
  int row = blockIdx.x * 4 + w;
  const float* xr = xin + (size_t)row * 512 + l * 8;
  f32x4 a = *(const f32x4*)xr;
  f32x4 b2 = *(const f32x4*)(xr + 4);
  float s = a[0]+a[1]+a[2]+a[3]+b2[0]+b2[1]+b2[2]+b2[3];
  #pragma unroll
  for (int m = 1; m < 64; m <<= 1) s += __shfl_xor(s, m, 64);
  float mu = s * (1.0f/512.0f);
  float vs = 0.f;
  #pragma unroll
  for (int i = 0; i < 4; i++) { float d = a[i]-mu; vs += d*d; d = b2[i]-mu; vs += d*d; }
  #pragma unroll
  for (int m = 1; m < 64; m <<= 1) vs += __shfl_xor(vs, m, 64);
  float rstd = rsqrtf(vs * (1.0f/512.0f) + 1e-5f);
  const float* gp = gamma + l*8;
  const float* bp = beta + l*8;
  f32x4 g0 = *(const f32x4*)gp, g1 = *(const f32x4*)(gp+4);
  f32x4 p0 = *(const f32x4*)bp, p1 = *(const f32x4*)(bp+4);
  bf16x8 h;
  #pragma unroll
  for (int i = 0; i < 4; i++) {
    h[i]   = (bf16_t)((a[i]-mu)*rstd*g0[i] + p0[i]);
    h[4+i] = (bf16_t)((b2[i]-mu)*rstd*g1[i] + p1[i]);
  }
  *(bf16x8*)(hout + (size_t)row*512 + l*8) = h;
}

// ---------------- weight transpose + cast: [K][N] f32 -> [N][K] bf16 ----------------
__global__ __launch_bounds__(256) void prep_kernel(
    const float* __restrict__ Wq, const float* __restrict__ Wk, const float* __restrict__ Wv,
    const float* __restrict__ Wo, const float* __restrict__ Wg, const float* __restrict__ Wf,
    bf16_t* __restrict__ WqkvT, bf16_t* __restrict__ WoT,
    bf16_t* __restrict__ WgT, bf16_t* __restrict__ WfT)
{
  __shared__ float tile[32][33];
  int z = blockIdx.z;
  const float* src; bf16_t* dst; int K = 512, N = 512;
  if (z < 12) {
    int lay = z & 3, which = z >> 2;  // 0..3:Wq 4..7:Wk 8..11:Wv
    src = (which == 0 ? Wq : which == 1 ? Wk : Wv) + (size_t)lay*512*512;
    dst = WqkvT + (size_t)lay*1536*512 + (size_t)which*512*512;
  } else if (z < 16) {
    src = Wo + (size_t)(z-12)*512*512;
    dst = WoT + (size_t)(z-12)*512*512;
  } else if (z == 16) { src = Wg; dst = WgT; }
  else { src = Wf; dst = WfT; K = 256; }
  int k0 = blockIdx.y*32, n0 = blockIdx.x*32;
  if (k0 >= K) return;  // uniform per block (Wf has K=256)
  int tx = threadIdx.x & 31, ty = threadIdx.x >> 5;
  #pragma unroll
  for (int j = 0; j < 4; j++)
    tile[ty + j*8][tx] = src[(size_t)(k0 + ty + j*8)*N + n0 + tx];
  __syncthreads();
  #pragma unroll
  for (int j = 0; j < 4; j++)
    dst[(size_t)(n0 + ty + j*8)*K + k0 + tx] = (bf16_t)tile[tx][ty + j*8];
}

// ---------------- GEMM: C[M x N] = A[M x K](bf16) * Bt[N x K](bf16)^T ----------------
// 128x128 tile, BK=64, 4 waves (2x2 of 64x64), 16x16x32 bf16 MFMA.
// EPI 0: bf16 out, cols<512 scaled by qscale (QKV).  EPI 1: f32 out + bias + resid.
// EPI 2: f32 out + bias.
template<int EPI>
__global__ __launch_bounds__(256) void gemm_bt(
    const bf16_t* __restrict__ A, const bf16_t* __restrict__ Bt,
    int N, int K,
    void* __restrict__ Cout, const float* __restrict__ bias,
    const float* __restrict__ resid, float qscale)
{
  __shared__ bf16_t As[128*64];
  __shared__ bf16_t Bs[128*64];
  int t = threadIdx.x, w = t >> 6, l = t & 63;
  int tm = blockIdx.y * 128, tn = blockIdx.x * 128;
  int wm = (w >> 1) * 64, wn = (w & 1) * 64;
  f32x4 acc[4][4] = {};
  int srow = l >> 3;                    // staging: 8 rows per 1KB inst
  int schunk = ((l & 7) ^ srow) * 8;    // XOR-swizzle via pre-swizzled global source
  for (int k0 = 0; k0 < K; k0 += 64) {
    __syncthreads();
    #pragma unroll
    for (int i = 0; i < 4; i++) {
      int rb = i*32 + w*8;
      gload_lds16(A  + (size_t)(tm + rb + srow)*K + k0 + schunk, &As[rb*64]);
      gload_lds16(Bt + (size_t)(tn + rb + srow)*K + k0 + schunk, &Bs[rb*64]);
    }
    __syncthreads();
    #pragma unroll
    for (int kk = 0; kk < 2; kk++) {
      bf16x8 af[4], bfr[4];
      #pragma unroll
      for (int mf = 0; mf < 4; mf++) {
        int row = wm + mf*16 + (l & 15);
        int off = (kk*32 + (l >> 4)*8) ^ ((row & 7) << 3);
        af[mf] = *(const bf16x8*)&As[row*64 + off];
      }
      #pragma unroll
      for (int nf = 0; nf < 4; nf++) {
        int row = wn + nf*16 + (l & 15);
        int off = (kk*32 + (l >> 4)*8) ^ ((row & 7) << 3);
        bfr[nf] = *(const bf16x8*)&Bs[row*64 + off];
      }
      #pragma unroll
      for (int mf = 0; mf < 4; mf++)
        #pragma unroll
        for (int nf = 0; nf < 4; nf++)
          acc[mf][nf] = __builtin_amdgcn_mfma_f32_16x16x32_bf16(af[mf], bfr[nf], acc[mf][nf], 0, 0, 0);
    }
  }
  int colb = tn + wn + (l & 15);
  int rowb = tm + wm + ((l >> 4) << 2);
  #pragma unroll
  for (int mf = 0; mf < 4; mf++)
    #pragma unroll
    for (int nf = 0; nf < 4; nf++)
      #pragma unroll
      for (int r = 0; r < 4; r++) {
        int row = rowb + mf*16 + r;
        int col = colb + nf*16;
        float v = acc[mf][nf][r];
        if (EPI == 0) {
          if (col < 512) v *= qscale;
          ((bf16_t*)Cout)[(size_t)row*N + col] = (bf16_t)v;
        } else if (EPI == 1) {
          ((float*)Cout)[(size_t)row*N + col] = v + bias[col] + resid[(size_t)row*N + col];
        } else {
          ((float*)Cout)[(size_t)row*N + col] = v + bias[col];
        }
      }
}

// ---------------- fused flash attention ----------------
// grid (S/64, H, B); 256 threads = 4 waves; wave w owns q-rows w*16..w*16+15.
// qkv layout: [B*S][1536] bf16, q cols 0..511 (pre-scaled by 1/8), k 512.., v 1024..
__global__ __launch_bounds__(256) void attn_kernel(const bf16_t* __restrict__ qkv,
                                                   bf16_t* __restrict__ obuf)
{
  __shared__ bf16_t Qs[64*64];   // swizzled
  __shared__ bf16_t Ks[64*64];   // swizzled
  __shared__ bf16_t VT[64*72];   // V transposed [ch][kv], stride 72
  __shared__ bf16_t Ps[4*16*72]; // per-wave P, stride 72
  int t = threadIdx.x, w = t >> 6, l = t & 63;
  int q0 = blockIdx.x * 64, h = blockIdx.y, b = blockIdx.z;
  size_t rbase = (size_t)b * 2048;
  int srow = l >> 3;
  int schunk = ((l & 7) ^ srow) * 8;
  const bf16_t* qb = qkv + (rbase + q0) * 1536 + h*64;
  #pragma unroll
  for (int i = 0; i < 2; i++) {
    int rb = w*16 + i*8;
    gload_lds16(qb + (size_t)(rb + srow)*1536 + schunk, &Qs[rb*64]);
  }
  const bf16_t* kb = qkv + rbase*1536 + 512 + h*64;
  const bf16_t* vb = qkv + rbase*1536 + 1024 + h*64;
  float m_r[4], l_r[4];
  #pragma unroll
  for (int r = 0; r < 4; r++) { m_r[r] = -1e30f; l_r[r] = 0.f; }
  f32x4 accO[4] = {};
  int vch0 = w * 16;
  int pw = w * 16 * 72;
  for (int kv0 = 0; kv0 < 2048; kv0 += 64) {
    __syncthreads();  // prev tile consumed (also drains Q staging on iter 0)
    #pragma unroll
    for (int i = 0; i < 2; i++) {
      int rb = w*16 + i*8;
      gload_lds16(kb + (size_t)(kv0 + rb + srow)*1536 + schunk, &Ks[rb*64]);
    }
    { // V transpose stage: lane reads 16 ch of row kv0+l, writes VT[ch][l]
      const bf16_t* vp = vb + (size_t)(kv0 + l)*1536 + vch0;
      bf16x8 v0 = *(const bf16x8*)vp;
      bf16x8 v1 = *(const bf16x8*)(vp + 8);
      #pragma unroll
      for (int e = 0; e < 8; e++) {
        VT[(vch0 + e)*72 + l] = v0[e];
        VT[(vch0 + 8 + e)*72 + l] = v1[e];
      }
    }
    __syncthreads();
    // S = Q K^T  (16q x 64kv per wave)
    f32x4 s[4] = {};
    #pragma unroll
    for (int kk = 0; kk < 2; kk++) {
      int off = (kk*32 + (l >> 4)*8) ^ ((l & 7) << 3);
      bf16x8 aq = *(const bf16x8*)&Qs[(w*16 + (l & 15))*64 + off];
      #pragma unroll
      for (int nf = 0; nf < 4; nf++) {
        bf16x8 bk = *(const bf16x8*)&Ks[(nf*16 + (l & 15))*64 + off];
        s[nf] = __builtin_amdgcn_mfma_f32_16x16x32_bf16(aq, bk, s[nf], 0, 0, 0);
      }
    }
    // online softmax: row r lives in 16-lane group (l>>4 fixed), reduce over l&15
    float tmx[4];
    #pragma unroll
    for (int r = 0; r < 4; r++)
      tmx[r] = fmaxf(fmaxf(s[0][r], s[1][r]), fmaxf(s[2][r], s[3][r]));
    #pragma unroll
    for (int msk = 1; msk < 16; msk <<= 1)
      #pragma unroll
      for (int r = 0; r < 4; r++)
        tmx[r] = fmaxf(tmx[r], __shfl_xor(tmx[r], msk, 64));
    float corr[4], rs4[4];
    #pragma unroll
    for (int r = 0; r < 4; r++) {
      float mn = fmaxf(m_r[r], tmx[r]);
      corr[r] = exp2f((m_r[r] - mn) * 1.44269504f);
      m_r[r] = mn;
      rs4[r] = 0.f;
    }
    #pragma unroll
    for (int nf = 0; nf < 4; nf++)
      #pragma unroll
      for (int r = 0; r < 4; r++) {
        float p = exp2f((s[nf][r] - m_r[r]) * 1.44269504f);
        s[nf][r] = p;
        rs4[r] += p;
      }
    #pragma unroll
    for (int msk = 1; msk < 16; msk <<= 1)
      #pragma unroll
      for (int r = 0; r < 4; r++)
        rs4[r] += __shfl_xor(rs4[r], msk, 64);
    #pragma unroll
    for (int r = 0; r < 4; r++)
      l_r[r] = l_r[r]*corr[r] + rs4[r];
    #pragma unroll
    for (int nf = 0; nf < 4; nf++)
      #pragma unroll
      for (int r = 0; r < 4; r++)
        accO[nf][r] *= corr[r];
    // P (C/D layout) -> LDS -> A-operand layout; wave-private, no barrier needed
    #pragma unroll
    for (int nf = 0; nf < 4; nf++)
      #pragma unroll
      for (int r = 0; r < 4; r++)
        Ps[pw + ((l >> 4)*4 + r)*72 + nf*16 + (l & 15)] = (bf16_t)s[nf][r];
    #pragma unroll
    for (int kk = 0; kk < 2; kk++) {
      bf16x8 pa = *(const bf16x8*)&Ps[pw + (l & 15)*72 + kk*32 + (l >> 4)*8];
      #pragma unroll
      for (int nf = 0; nf < 4; nf++) {
        bf16x8 vv = *(const bf16x8*)&VT[(nf*16 + (l & 15))*72 + kk*32 + (l >> 4)*8];
        accO[nf] = __builtin_amdgcn_mfma_f32_16x16x32_bf16(pa, vv, accO[nf], 0, 0, 0);
      }
    }
  }
  #pragma unroll
  for (int r = 0; r < 4; r++) l_r[r] = 1.0f / l_r[r];
  size_t orow = rbase + q0 + w*16 + ((l >> 4)*4);
  #pragma unroll
  for (int nf = 0; nf < 4; nf++)
    #pragma unroll
    for (int r = 0; r < 4; r++)
      obuf[(orow + r)*512 + h*64 + nf*16 + (l & 15)] = (bf16_t)(accO[nf][r] * l_r[r]);
}

// ---------------- gated gelu: ff = a * gelu(gate), g already has +bg ----------------
__global__ __launch_bounds__(256) void gelu_kernel(const float* __restrict__ g,
                                                   bf16_t* __restrict__ ff)
{
  int idx = blockIdx.x * 256 + threadIdx.x;  // 262144 threads, 4 outputs each
  int row = idx >> 6;
  int c = (idx & 63) * 4;
  const float* gr = g + (size_t)row*512;
  f32x4 a = *(const f32x4*)(gr + c);
  f32x4 u = *(const f32x4*)(gr + 256 + c);
  bf16x4 o4;
  #pragma unroll
  for (int i = 0; i < 4; i++) {
    float x = u[i];
    float tt = tanhf(0.7978845608f * x * (1.0f + 0.044715f * x * x));
    o4[i] = (bf16_t)(a[i] * 0.5f * x * (1.0f + tt));
  }
  *(bf16x4*)(ff + (size_t)row*256 + c) = o4;
}

// ---------------- launcher ----------------
extern "C" void kernel_launch(void* const* d_in, const int* in_sizes, int n_in,
                              void* d_out, int out_size, void* d_ws, size_t ws_size,
                              hipStream_t stream)
{
  const float* x     = (const float*)d_in[0];
  const float* gamma = (const float*)d_in[1];
  const float* beta  = (const float*)d_in[2];
  const float* Wq    = (const float*)d_in[3];
  const float* Wk    = (const float*)d_in[4];
  const float* Wv    = (const float*)d_in[5];
  const float* Wo    = (const float*)d_in[6];
  const float* bo    = (const float*)d_in[7];
  const float* Wg    = (const float*)d_in[8];
  const float* bg    = (const float*)d_in[9];
  const float* Wf    = (const float*)d_in[10];
  const float* bf    = (const float*)d_in[11];

  char* ws = (char*)d_ws;
  float*  xcur  = (float*)ws;                            // 8 MB  f32 [4096][512]
  bf16_t* hbuf  = (bf16_t*)(ws + (8u<<20));              // 4 MB  bf16 [4096][512]
  bf16_t* qkv   = (bf16_t*)(ws + (12u<<20));             // 12 MB bf16 [4096][1536]
  bf16_t* obuf  = (bf16_t*)(ws + (24u<<20));             // 4 MB  bf16 [4096][512]
  bf16_t* WqkvT = (bf16_t*)(ws + (28u<<20));             // 6 MB
  bf16_t* WoT   = (bf16_t*)(ws + (34u<<20));             // 2 MB
  bf16_t* WgT   = (bf16_t*)(ws + (36u<<20));             // 0.5 MB
  bf16_t* WfT   = (bf16_t*)(ws + (36u<<20) + (512u<<10));// 0.25 MB
  float*  gbuf  = (float*)qkv;   // reuse (qkv dead by MLP)
  bf16_t* ffb   = obuf;          // reuse (o dead by MLP)

  prep_kernel<<<dim3(16,16,18), 256, 0, stream>>>(Wq,Wk,Wv,Wo,Wg,Wf,WqkvT,WoT,WgT,WfT);
  hipMemcpyAsync(xcur, x, (size_t)MROWS*512*4, hipMemcpyDeviceToDevice, stream);

  for (int lay = 0; lay < 4; lay++) {
    ln_kernel<<<1024, 256, 0, stream>>>(xcur, gamma + lay*512, beta + lay*512, hbuf);
    gemm_bt<0><<<dim3(12,32), 256, 0, stream>>>(hbuf, WqkvT + (size_t)lay*1536*512,
                                                1536, 512, qkv, nullptr, nullptr, 0.125f);
    attn_kernel<<<dim3(32,8,2), 256, 0, stream>>>(qkv, obuf);
    gemm_bt<1><<<dim3(4,32), 256, 0, stream>>>(obuf, WoT + (size_t)lay*512*512,
                                               512, 512, xcur, bo + lay*512, xcur, 1.0f);
  }
  ln_kernel<<<1024, 256, 0, stream>>>(xcur, gamma + 4*512, beta + 4*512, hbuf);
  gemm_bt<2><<<dim3(4,32), 256, 0, stream>>>(hbuf, WgT, 512, 512, gbuf, bg, nullptr, 1.0f);
  gelu_kernel<<<1024, 256, 0, stream>>>(gbuf, ffb);
  gemm_bt<1><<<dim3(4,32), 256, 0, stream>>>(ffb, WfT, 512, 256, d_out, bf, xcur, 1.0f);
}

// Round 4
// 442.556 us; speedup vs baseline: 1.3896x; 1.3896x over previous
//
#include <hip/hip_runtime.h>
#include <hip/hip_bf16.h>

// Basic_Transformer on MI355X (gfx950): bf16 MFMA pipeline.
// B=2 S=2048 C=512 L=4 H=8 CH=64 OD=256; rows M = B*S = 4096.

typedef __bf16 bf16_t;
typedef __attribute__((ext_vector_type(8))) __bf16 bf16x8;
typedef __attribute__((ext_vector_type(4))) __bf16 bf16x4;
typedef __attribute__((ext_vector_type(4))) float f32x4;

#define MROWS 4096

static __device__ __forceinline__ void gload_lds16(const void* g, void* l) {
  __builtin_amdgcn_global_load_lds((const __attribute__((address_space(1))) void*)g,
                                   (__attribute__((address_space(3))) void*)l, 16, 0, 0);
}

// ---------------- layernorm: one wave per row (64 lanes x 8 f32) ----------------
__global__ __launch_bounds__(256) void ln_kernel(const float* __restrict__ xin,
    const float* __restrict__ gamma, const float* __restrict__ beta,
    bf16_t* __restrict__ hout)
{
  int w = threadIdx.x >> 6, l = threadIdx.x & 63;
  int row = blockIdx.x * 4 + w;
  const float* xr = xin + (size_t)row * 512 + l * 8;
  f32x4 a = *(const f32x4*)xr;
  f32x4 b2 = *(const f32x4*)(xr + 4);
  float s = a[0]+a[1]+a[2]+a[3]+b2[0]+b2[1]+b2[2]+b2[3];
  #pragma unroll
  for (int m = 1; m < 64; m <<= 1) s += __shfl_xor(s, m, 64);
  float mu = s * (1.0f/512.0f);
  float vs = 0.f;
  #pragma unroll
  for (int i = 0; i < 4; i++) { float d = a[i]-mu; vs += d*d; d = b2[i]-mu; vs += d*d; }
  #pragma unroll
  for (int m = 1; m < 64; m <<= 1) vs += __shfl_xor(vs, m, 64);
  float rstd = rsqrtf(vs * (1.0f/512.0f) + 1e-5f);
  const float* gp = gamma + l*8;
  const float* bp = beta + l*8;
  f32x4 g0 = *(const f32x4*)gp, g1 = *(const f32x4*)(gp+4);
  f32x4 p0 = *(const f32x4*)bp, p1 = *(const f32x4*)(bp+4);
  bf16x8 h;
  #pragma unroll
  for (int i = 0; i < 4; i++) {
    h[i]   = (bf16_t)((a[i]-mu)*rstd*g0[i] + p0[i]);
    h[4+i] = (bf16_t)((b2[i]-mu)*rstd*g1[i] + p1[i]);
  }
  *(bf16x8*)(hout + (size_t)row*512 + l*8) = h;
}

// ---------------- weight transpose + cast: [K][N] f32 -> [N][K] bf16 ----------------
__global__ __launch_bounds__(256) void prep_kernel(
    const float* __restrict__ Wq, const float* __restrict__ Wk, const float* __restrict__ Wv,
    const float* __restrict__ Wo, const float* __restrict__ Wg, const float* __restrict__ Wf,
    bf16_t* __restrict__ WqkvT, bf16_t* __restrict__ WoT,
    bf16_t* __restrict__ WgT, bf16_t* __restrict__ WfT)
{
  __shared__ float tile[32][33];
  int z = blockIdx.z;
  const float* src; bf16_t* dst; int K = 512, N = 512;
  if (z < 12) {
    int lay = z & 3, which = z >> 2;  // 0..3:Wq 4..7:Wk 8..11:Wv
    src = (which == 0 ? Wq : which == 1 ? Wk : Wv) + (size_t)lay*512*512;
    dst = WqkvT + (size_t)lay*1536*512 + (size_t)which*512*512;
  } else if (z < 16) {
    src = Wo + (size_t)(z-12)*512*512;
    dst = WoT + (size_t)(z-12)*512*512;
  } else if (z == 16) { src = Wg; dst = WgT; }
  else { src = Wf; dst = WfT; K = 256; }
  int k0 = blockIdx.y*32, n0 = blockIdx.x*32;
  if (k0 >= K) return;  // uniform per block (Wf has K=256)
  int tx = threadIdx.x & 31, ty = threadIdx.x >> 5;
  #pragma unroll
  for (int j = 0; j < 4; j++)
    tile[ty + j*8][tx] = src[(size_t)(k0 + ty + j*8)*N + n0 + tx];
  __syncthreads();
  #pragma unroll
  for (int j = 0; j < 4; j++)
    dst[(size_t)(n0 + ty + j*8)*K + k0 + tx] = (bf16_t)tile[tx][ty + j*8];
}

// ---------------- GEMM: C[M x N] = A[M x K](bf16) * Bt[N x K](bf16)^T ----------------
// 128x128 tile, BK=64, 4 waves (2x2 of 64x64), 16x16x32 bf16 MFMA.
// EPI 0: QKV. cols<512 (q) scaled by qscale -> qkv[row][1024]; cols 512..1023 (k)
//        plain -> qkv; cols>=1024 (v) -> vT[b][h][ch][2048] (pre-transposed).
// EPI 1: f32 out + bias + resid.  EPI 2: f32 out + bias.
template<int EPI>
__global__ __launch_bounds__(256) void gemm_bt(
    const bf16_t* __restrict__ A, const bf16_t* __restrict__ Bt,
    int N, int K,
    void* __restrict__ Cout, bf16_t* __restrict__ vTout,
    const float* __restrict__ bias, const float* __restrict__ resid, float qscale)
{
  __shared__ bf16_t As[128*64];
  __shared__ bf16_t Bs[128*64];
  int t = threadIdx.x, w = t >> 6, l = t & 63;
  int tm = blockIdx.y * 128, tn = blockIdx.x * 128;
  int wm = (w >> 1) * 64, wn = (w & 1) * 64;
  f32x4 acc[4][4] = {};
  int srow = l >> 3;                    // staging: 8 rows per 1KB inst
  int schunk = ((l & 7) ^ srow) * 8;    // XOR-swizzle via pre-swizzled global source
  for (int k0 = 0; k0 < K; k0 += 64) {
    __syncthreads();
    #pragma unroll
    for (int i = 0; i < 4; i++) {
      int rb = i*32 + w*8;
      gload_lds16(A  + (size_t)(tm + rb + srow)*K + k0 + schunk, &As[rb*64]);
      gload_lds16(Bt + (size_t)(tn + rb + srow)*K + k0 + schunk, &Bs[rb*64]);
    }
    __syncthreads();
    #pragma unroll
    for (int kk = 0; kk < 2; kk++) {
      bf16x8 af[4], bfr[4];
      #pragma unroll
      for (int mf = 0; mf < 4; mf++) {
        int row = wm + mf*16 + (l & 15);
        int off = (kk*32 + (l >> 4)*8) ^ ((row & 7) << 3);
        af[mf] = *(const bf16x8*)&As[row*64 + off];
      }
      #pragma unroll
      for (int nf = 0; nf < 4; nf++) {
        int row = wn + nf*16 + (l & 15);
        int off = (kk*32 + (l >> 4)*8) ^ ((row & 7) << 3);
        bfr[nf] = *(const bf16x8*)&Bs[row*64 + off];
      }
      #pragma unroll
      for (int mf = 0; mf < 4; mf++)
        #pragma unroll
        for (int nf = 0; nf < 4; nf++)
          acc[mf][nf] = __builtin_amdgcn_mfma_f32_16x16x32_bf16(af[mf], bfr[nf], acc[mf][nf], 0, 0, 0);
    }
  }
  int colb = tn + wn + (l & 15);
  int rowb = tm + wm + ((l >> 4) << 2);
  if (EPI == 0 && tn >= 1024) {
    // v region -> vT[b][h][ch][2048], vectorized over 4 consecutive s
    #pragma unroll
    for (int mf = 0; mf < 4; mf++)
      #pragma unroll
      for (int nf = 0; nf < 4; nf++) {
        int col = colb + nf*16;
        int hh = (col - 1024) >> 6, ch = (col - 1024) & 63;
        int row = rowb + mf*16;
        int bb = row >> 11, sdx = row & 2047;
        bf16x4 pk;
        #pragma unroll
        for (int r = 0; r < 4; r++) pk[r] = (bf16_t)acc[mf][nf][r];
        *(bf16x4*)&vTout[(((size_t)bb*8 + hh)*64 + ch)*2048 + sdx] = pk;
      }
    return;
  }
  #pragma unroll
  for (int mf = 0; mf < 4; mf++)
    #pragma unroll
    for (int nf = 0; nf < 4; nf++)
      #pragma unroll
      for (int r = 0; r < 4; r++) {
        int row = rowb + mf*16 + r;
        int col = colb + nf*16;
        float v = acc[mf][nf][r];
        if (EPI == 0) {
          if (col < 512) v *= qscale;
          ((bf16_t*)Cout)[(size_t)row*1024 + col] = (bf16_t)v;
        } else if (EPI == 1) {
          ((float*)Cout)[(size_t)row*N + col] = v + bias[col] + resid[(size_t)row*N + col];
        } else {
          ((float*)Cout)[(size_t)row*N + col] = v + bias[col];
        }
      }
}

// ---------------- fused flash attention (no-max softmax, pre-transposed V) ----------
// grid (S/64, H, B); 256 threads = 4 waves; wave w owns q-rows w*16..w*16+15.
// qkv layout: [B*S][1024] bf16: q cols 0..511 (pre-scaled by 0.125*log2e), k 512..1023.
// vT layout: [B][H][64 ch][2048 s] bf16.
__global__ __launch_bounds__(256) void attn_kernel(const bf16_t* __restrict__ qkv,
                                                   const bf16_t* __restrict__ vT,
                                                   bf16_t* __restrict__ obuf)
{
  __shared__ bf16_t Qs[64*64];
  __shared__ bf16_t Ks[2][64*64];
  __shared__ bf16_t Vs[2][64*64];   // V^T tile: [ch][kv], swizzled
  __shared__ bf16_t Ps[4*16*72];    // per-wave P, stride 72
  int t = threadIdx.x, w = t >> 6, l = t & 63;
  int q0 = blockIdx.x * 64, h = blockIdx.y, b = blockIdx.z;
  size_t rbase = (size_t)b * 2048;
  int srow = l >> 3;
  int schunk = ((l & 7) ^ srow) * 8;
  int rb0 = w*16, rb1 = w*16 + 8;
  // Q stage (once)
  const bf16_t* qb = qkv + (rbase + q0) * 1024 + h*64;
  gload_lds16(qb + (size_t)(rb0 + srow)*1024 + schunk, &Qs[rb0*64]);
  gload_lds16(qb + (size_t)(rb1 + srow)*1024 + schunk, &Qs[rb1*64]);
  const bf16_t* kb  = qkv + rbase*1024 + 512 + h*64;
  const bf16_t* vtb = vT + ((size_t)(b*8 + h)*64)*2048;
  // stage tile 0
  gload_lds16(kb + (size_t)(rb0 + srow)*1024 + schunk, &Ks[0][rb0*64]);
  gload_lds16(kb + (size_t)(rb1 + srow)*1024 + schunk, &Ks[0][rb1*64]);
  gload_lds16(vtb + (size_t)(rb0 + srow)*2048 + schunk, &Vs[0][rb0*64]);
  gload_lds16(vtb + (size_t)(rb1 + srow)*2048 + schunk, &Vs[0][rb1*64]);

  int lq = l & 15, hi = l >> 4;
  int pw = w * 16 * 72;
  f32x4 accO[4] = {};
  f32x4 lacc = {};
  bf16x8 aq[2];
  bf16x8 ones;
  #pragma unroll
  for (int e = 0; e < 8; e++) ones[e] = (bf16_t)1.0f;
  int qrow = w*16 + lq;
  int swz = (lq & 7) << 3;

  for (int tt = 0; tt < 32; ++tt) {
    int cur = tt & 1;
    if (tt < 31) {
      int kv1 = (tt + 1) * 64;
      int nxt = cur ^ 1;
      gload_lds16(kb + (size_t)(kv1 + rb0 + srow)*1024 + schunk, &Ks[nxt][rb0*64]);
      gload_lds16(kb + (size_t)(kv1 + rb1 + srow)*1024 + schunk, &Ks[nxt][rb1*64]);
      gload_lds16(vtb + (size_t)(rb0 + srow)*2048 + kv1 + schunk, &Vs[nxt][rb0*64]);
      gload_lds16(vtb + (size_t)(rb1 + srow)*2048 + kv1 + schunk, &Vs[nxt][rb1*64]);
      asm volatile("s_waitcnt vmcnt(4)" ::: "memory");  // current tile's 4 landed
    } else {
      asm volatile("s_waitcnt vmcnt(0)" ::: "memory");
    }
    __builtin_amdgcn_s_barrier();
    if (tt == 0) {  // Q landed with tile 0; hoist fragments to regs once
      aq[0] = *(const bf16x8*)&Qs[qrow*64 + ((hi*8) ^ swz)];
      aq[1] = *(const bf16x8*)&Qs[qrow*64 + ((32 + hi*8) ^ swz)];
    }
    // S~ = (q*0.125*log2e) . k   -> P = 2^S~
    f32x4 s4[4] = {};
    #pragma unroll
    for (int kk = 0; kk < 2; kk++) {
      int off = (kk*32 + hi*8) ^ swz;
      #pragma unroll
      for (int nf = 0; nf < 4; nf++) {
        bf16x8 bk = *(const bf16x8*)&Ks[cur][(nf*16 + lq)*64 + off];
        s4[nf] = __builtin_amdgcn_mfma_f32_16x16x32_bf16(aq[kk], bk, s4[nf], 0, 0, 0);
      }
    }
    #pragma unroll
    for (int nf = 0; nf < 4; nf++)
      #pragma unroll
      for (int r = 0; r < 4; r++)
        Ps[pw + (hi*4 + r)*72 + nf*16 + lq] = (bf16_t)exp2f(s4[nf][r]);
    // PV + row-sum (ones-MFMA); wave-private P, compiler orders write->read
    #pragma unroll
    for (int kk = 0; kk < 2; kk++) {
      int off = (kk*32 + hi*8) ^ swz;
      bf16x8 pa = *(const bf16x8*)&Ps[pw + lq*72 + kk*32 + hi*8];
      lacc = __builtin_amdgcn_mfma_f32_16x16x32_bf16(pa, ones, lacc, 0, 0, 0);
      #pragma unroll
      for (int nf = 0; nf < 4; nf++) {
        bf16x8 vv = *(const bf16x8*)&Vs[cur][(nf*16 + lq)*64 + off];
        accO[nf] = __builtin_amdgcn_mfma_f32_16x16x32_bf16(pa, vv, accO[nf], 0, 0, 0);
      }
    }
    asm volatile("s_waitcnt lgkmcnt(0)" ::: "memory");  // reads of buf done
    __builtin_amdgcn_s_barrier();                       // before next-stage overwrite
  }
  f32x4 linv;
  #pragma unroll
  for (int r = 0; r < 4; r++) linv[r] = 1.0f / lacc[r];
  size_t orow = rbase + q0 + w*16 + hi*4;
  #pragma unroll
  for (int nf = 0; nf < 4; nf++)
    #pragma unroll
    for (int r = 0; r < 4; r++)
      obuf[(orow + r)*512 + h*64 + nf*16 + lq] = (bf16_t)(accO[nf][r] * linv[r]);
}

// ---------------- gated gelu: ff = a * gelu(gate), g already has +bg ----------------
__global__ __launch_bounds__(256) void gelu_kernel(const float* __restrict__ g,
                                                   bf16_t* __restrict__ ff)
{
  int idx = blockIdx.x * 256 + threadIdx.x;  // 262144 threads, 4 outputs each
  int row = idx >> 6;
  int c = (idx & 63) * 4;
  const float* gr = g + (size_t)row*512;
  f32x4 a = *(const f32x4*)(gr + c);
  f32x4 u = *(const f32x4*)(gr + 256 + c);
  bf16x4 o4;
  #pragma unroll
  for (int i = 0; i < 4; i++) {
    float x = u[i];
    float tt = tanhf(0.7978845608f * x * (1.0f + 0.044715f * x * x));
    o4[i] = (bf16_t)(a[i] * 0.5f * x * (1.0f + tt));
  }
  *(bf16x4*)(ff + (size_t)row*256 + c) = o4;
}

// ---------------- launcher ----------------
extern "C" void kernel_launch(void* const* d_in, const int* in_sizes, int n_in,
                              void* d_out, int out_size, void* d_ws, size_t ws_size,
                              hipStream_t stream)
{
  const float* x     = (const float*)d_in[0];
  const float* gamma = (const float*)d_in[1];
  const float* beta  = (const float*)d_in[2];
  const float* Wq    = (const float*)d_in[3];
  const float* Wk    = (const float*)d_in[4];
  const float* Wv    = (const float*)d_in[5];
  const float* Wo    = (const float*)d_in[6];
  const float* bo    = (const float*)d_in[7];
  const float* Wg    = (const float*)d_in[8];
  const float* bg    = (const float*)d_in[9];
  const float* Wf    = (const float*)d_in[10];
  const float* bf    = (const float*)d_in[11];

  char* ws = (char*)d_ws;
  float*  xcur  = (float*)ws;                            // 0-8 MB   f32 [4096][512]
  bf16_t* hbuf  = (bf16_t*)(ws + (8u<<20));              // 8-12 MB  bf16 [4096][512]
  bf16_t* qkv   = (bf16_t*)(ws + (12u<<20));             // 12-20 MB bf16 [4096][1024] (q,k)
  bf16_t* vT    = (bf16_t*)(ws + (20u<<20));             // 20-24 MB bf16 [2][8][64][2048]
  bf16_t* obuf  = (bf16_t*)(ws + (24u<<20));             // 24-28 MB bf16 [4096][512]
  bf16_t* WqkvT = (bf16_t*)(ws + (28u<<20));             // 28-34 MB
  bf16_t* WoT   = (bf16_t*)(ws + (34u<<20));             // 34-36 MB
  bf16_t* WgT   = (bf16_t*)(ws + (36u<<20));             // 0.5 MB
  bf16_t* WfT   = (bf16_t*)(ws + (36u<<20) + (512u<<10));// 0.25 MB
  float*  gbuf  = (float*)qkv;   // reuse (qkv dead by MLP)
  bf16_t* ffb   = obuf;          // reuse (o dead by MLP)

  const float QSCALE = 0.125f * 1.44269504f;  // fold 1/sqrt(CH) and log2(e) into q

  prep_kernel<<<dim3(16,16,18), 256, 0, stream>>>(Wq,Wk,Wv,Wo,Wg,Wf,WqkvT,WoT,WgT,WfT);
  hipMemcpyAsync(xcur, x, (size_t)MROWS*512*4, hipMemcpyDeviceToDevice, stream);

  for (int lay = 0; lay < 4; lay++) {
    ln_kernel<<<1024, 256, 0, stream>>>(xcur, gamma + lay*512, beta + lay*512, hbuf);
    gemm_bt<0><<<dim3(12,32), 256, 0, stream>>>(hbuf, WqkvT + (size_t)lay*1536*512,
                                                1536, 512, qkv, vT, nullptr, nullptr, QSCALE);
    attn_kernel<<<dim3(32,8,2), 256, 0, stream>>>(qkv, vT, obuf);
    gemm_bt<1><<<dim3(4,32), 256, 0, stream>>>(obuf, WoT + (size_t)lay*512*512,
                                               512, 512, xcur, nullptr, bo + lay*512, xcur, 1.0f);
  }
  ln_kernel<<<1024, 256, 0, stream>>>(xcur, gamma + 4*512, beta + 4*512, hbuf);
  gemm_bt<2><<<dim3(4,32), 256, 0, stream>>>(hbuf, WgT, 512, 512, gbuf, nullptr, bg, nullptr, 1.0f);
  gelu_kernel<<<1024, 256, 0, stream>>>(gbuf, ffb);
  gemm_bt<1><<<dim3(4,32), 256, 0, stream>>>(ffb, WfT, 512, 256, d_out, nullptr, bf, xcur, 1.0f);
}